// Round 2
// baseline (2193.928 us; speedup 1.0000x reference)
//
#include <hip/hip_runtime.h>
#include <math.h>

typedef unsigned short u16;
typedef unsigned int u32;

// ---- problem constants ----
constexpr int Bb = 4, Ll = 2048, DM = 1024, DI = 2048, DS = 16, DTR = 64, KC = 4;
constexpr int M = Bb * Ll;            // 8192 rows
constexpr int NPAD = 128;             // padded x_dbl width (64 + 2*16 = 96 -> 128)

// ---- bf16 helpers on raw u16 ----
__device__ __forceinline__ float b2f(u16 u) {
    return __uint_as_float(((u32)u) << 16);
}
__device__ __forceinline__ u16 f2b(float f) {
    u32 x = __float_as_uint(f);
    u32 r = (x + 0x7fffu + ((x >> 16) & 1u)) >> 16;   // round-to-nearest-even
    return (u16)r;
}

typedef __attribute__((ext_vector_type(8))) short short8;
typedef __attribute__((ext_vector_type(4))) float floatx4;

// =====================================================================
// C(MxN) = A(MxK) * B(NxK)^T, bf16 in, fp32 MFMA acc.
// Block = 256 thr = 4 waves, each wave 64x64, block tile 128x128.
// OUTM: 0 = bf16 store, 1 = fp32 store, 2 = softplus(acc + bias_f32[n]) bf16
// =====================================================================
template<int OUTM>
__global__ __launch_bounds__(256) void gemm_bt(
    const u16* __restrict__ A, const u16* __restrict__ Bm,
    void* __restrict__ Cv, const float* __restrict__ bias,
    int K, int lda, int ldb, int ldc)
{
    const int lane = threadIdx.x & 63;
    const int wave = threadIdx.x >> 6;
    const int wr = wave >> 1, wc = wave & 1;
    const int m0 = blockIdx.y * 128 + wr * 64;
    const int n0 = blockIdx.x * 128 + wc * 64;
    const int r16 = lane & 15;        // row within 16 (A rows / B rows)
    const int quad = lane >> 4;       // k-quad
    const int kbase = quad * 8;

    floatx4 acc[4][4] = {};

    const u16* Aptr = A + (size_t)(m0 + r16) * lda + kbase;
    const u16* Bptr = Bm + (size_t)(n0 + r16) * ldb + kbase;

    for (int k = 0; k < K; k += 32) {
        short8 af[4], bf[4];
#pragma unroll
        for (int i = 0; i < 4; i++)
            af[i] = *(const short8*)(Aptr + (size_t)(i * 16) * lda + k);
#pragma unroll
        for (int j = 0; j < 4; j++)
            bf[j] = *(const short8*)(Bptr + (size_t)(j * 16) * ldb + k);
#pragma unroll
        for (int i = 0; i < 4; i++)
#pragma unroll
            for (int j = 0; j < 4; j++)
                acc[i][j] = __builtin_amdgcn_mfma_f32_16x16x32_bf16(
                    af[i], bf[j], acc[i][j], 0, 0, 0);
    }

    // D layout: col = lane&15, row = quad*4 + r   [verified m89/m91]
    const int col = lane & 15;
    const int rb = quad * 4;
#pragma unroll
    for (int i = 0; i < 4; i++) {
#pragma unroll
        for (int j = 0; j < 4; j++) {
            const int n = n0 + j * 16 + col;
#pragma unroll
            for (int r = 0; r < 4; r++) {
                const int m = m0 + i * 16 + rb + r;
                float v = acc[i][j][r];
                if (OUTM == 2) {
                    v += bias[n];
                    v = (v > 20.f) ? v : log1pf(__expf(v));
                }
                if (OUTM == 1)
                    ((float*)Cv)[(size_t)m * ldc + n] = v;
                else
                    ((u16*)Cv)[(size_t)m * ldc + n] = f2b(v);
            }
        }
    }
}

// =====================================================================
// fp32 -> bf16 elementwise conversion
// =====================================================================
__global__ __launch_bounds__(256) void cvt_f2b(
    const float* __restrict__ in, u16* __restrict__ out, int n)
{
    int i = blockIdx.x * blockDim.x + threadIdx.x;
    if (i < n) out[i] = f2b(in[i]);
}

// =====================================================================
// Pad W_x (96 x 2048 fp32) into bf16 (128 x 2048), zero rows 96..127
// =====================================================================
__global__ __launch_bounds__(256) void pad_wx(
    const float* __restrict__ W_x, u16* __restrict__ out)
{
    int idx = blockIdx.x * blockDim.x + threadIdx.x;   // over 128*2048
    int r = idx >> 11;         // / 2048
    int c = idx & 2047;
    out[idx] = (r < 96) ? f2b(W_x[r * 2048 + c]) : (u16)0;
}

// =====================================================================
// Depthwise causal conv (K=4) + SiLU.  xr (M x DI bf16) -> xs (M x DI bf16)
// =====================================================================
__global__ __launch_bounds__(256) void conv_silu(
    const u16* __restrict__ xr, const float* __restrict__ conv_w,
    const float* __restrict__ conv_b, u16* __restrict__ xs)
{
    int idx = blockIdx.x * blockDim.x + threadIdx.x;   // over M*DI
    int m = idx >> 11;          // row in [0, M)
    int d = idx & 2047;
    int l = m & (Ll - 1);       // position within sequence (Ll pow2)

    float acc = conv_b[d];
#pragma unroll
    for (int k = 0; k < KC; k++) {
        int li = l - (KC - 1) + k;
        if (li >= 0)
            acc += b2f(xr[(size_t)(m - (KC - 1) + k) * DI + d]) * conv_w[d * KC + k];
    }
    float s = acc / (1.f + __expf(-acc));   // silu
    xs[(size_t)m * DI + d] = f2b(s);
}

// =====================================================================
// Selective scan.  16 lanes per channel (one per state), h in registers.
// channels = B*DI = 8192; block 256 thr -> 16 channels/block (4 per wave).
// Fuses y = scan + D*x and gate yg = y * silu(z).  yg may alias xs:
// all 16 lanes read xs[m,d] in lockstep before lane 0 overwrites it.
// =====================================================================
__global__ __launch_bounds__(256) void scan_kernel(
    const u16* __restrict__ dtb, const u16* xs, const u16* __restrict__ xdbl,
    const u16* __restrict__ z, const float* __restrict__ A_log,
    const float* __restrict__ Dvec, u16* yg)
{
    const int s = threadIdx.x & 15;
    const int ch = blockIdx.x * 16 + (threadIdx.x >> 4);
    const int b = ch >> 11;            // / DI
    const int d = ch & (DI - 1);

    const float adiag = -__expf(A_log[s]);
    const float Dd = Dvec[d];

    size_t row0 = (size_t)b * Ll;
    const u16* dt_p = dtb + row0 * DI + d;
    const u16* xs_p = xs + row0 * DI + d;
    const u16* z_p  = z + row0 * DI + d;
    const u16* bc_p = xdbl + row0 * NPAD;  // B at +64+s, C at +80+s
    u16* yg_p = yg + row0 * DI + d;

    float h = 0.f;
    for (int l = 0; l < Ll; l++) {
        float dtv = b2f(dt_p[0]);
        float xv  = b2f(xs_p[0]);
        float Bv  = b2f(bc_p[64 + s]);
        float Cv  = b2f(bc_p[80 + s]);

        float a = __expf(dtv * adiag);
        h = a * h + (dtv * xv) * Bv;

        float p = h * Cv;
        p += __shfl_xor(p, 1);
        p += __shfl_xor(p, 2);
        p += __shfl_xor(p, 4);
        p += __shfl_xor(p, 8);

        if (s == 0) {
            float y = p + Dd * xv;
            float zv = b2f(z_p[0]);
            float g = zv / (1.f + __expf(-zv));
            yg_p[0] = f2b(y * g);
        }
        dt_p += DI; xs_p += DI; z_p += DI; bc_p += NPAD; yg_p += DI;
    }
}

// =====================================================================
extern "C" void kernel_launch(void* const* d_in, const int* in_sizes, int n_in,
                              void* d_out, int out_size, void* d_ws, size_t ws_size,
                              hipStream_t stream)
{
    const float* x      = (const float*)d_in[0];   // (B,L,DM)
    const float* W_in   = (const float*)d_in[1];   // (2*DI, DM)
    const float* conv_w = (const float*)d_in[2];   // (DI, KC)
    const float* conv_b = (const float*)d_in[3];   // (DI,)
    const float* A_log  = (const float*)d_in[4];   // (DS,)
    const float* Dvec   = (const float*)d_in[5];   // (DI,)
    const float* W_x    = (const float*)d_in[6];   // (96, DI)
    const float* W_dt   = (const float*)d_in[7];   // (DI, DTR)
    const float* b_dt   = (const float*)d_in[8];   // (DI,)
    const float* W_out  = (const float*)d_in[9];   // (DM, DI)

    // ---- workspace arena (bf16 u16 elements), ~123 MB total ----
    u16* ws = (u16*)d_ws;
    u16* xr    = ws;                 ws += (size_t)M * DI;     // 33.5 MB (dead after conv -> reused as dtb)
    u16* z     = ws;                 ws += (size_t)M * DI;     // 33.5 MB
    u16* xs    = ws;                 ws += (size_t)M * DI;     // 33.5 MB (yg written in-place)
    u16* xbf   = ws;                 ws += (size_t)M * DM;     // 16.8 MB
    u16* wibf  = ws;                 ws += (size_t)DI * DM;    // 4.2 MB (W_in half, two passes)
    u16* wxp   = ws;                 ws += (size_t)NPAD * DI;  // 0.5 MB
    u16* wdtb  = ws;                 ws += (size_t)DI * DTR;   // 0.26 MB
    u16* woutb = ws;                 ws += (size_t)DM * DI;    // 4.2 MB
    u16* xdbl  = ws;                 ws += (size_t)M * NPAD;   // 2 MB
    u16* dtb   = xr;                                            // alias (xr dead by then)
    u16* yg    = xs;                                            // in-place

    // 0) conversions for GEMM1 operands
    cvt_f2b<<<(M * DM) / 256, 256, 0, stream>>>(x, xbf, M * DM);
    cvt_f2b<<<(DI * DM) / 256, 256, 0, stream>>>(W_in, wibf, DI * DM);

    // 1a) xr = x @ W_in[0:DI]^T   (8192 x 2048, K=1024)
    gemm_bt<0><<<dim3(DI / 128, M / 128), 256, 0, stream>>>(
        xbf, wibf, xr, nullptr, DM, DM, DM, DI);

    // 1b) z = x @ W_in[DI:2DI]^T
    cvt_f2b<<<(DI * DM) / 256, 256, 0, stream>>>(W_in + (size_t)DI * DM, wibf, DI * DM);
    gemm_bt<0><<<dim3(DI / 128, M / 128), 256, 0, stream>>>(
        xbf, wibf, z, nullptr, DM, DM, DM, DI);

    // 2) remaining weight conversions
    pad_wx<<<(NPAD * DI) / 256, 256, 0, stream>>>(W_x, wxp);
    cvt_f2b<<<(DI * DTR) / 256, 256, 0, stream>>>(W_dt, wdtb, DI * DTR);
    cvt_f2b<<<(DM * DI) / 256, 256, 0, stream>>>(W_out, woutb, DM * DI);

    // 3) conv + silu -> xs
    conv_silu<<<(M * DI) / 256, 256, 0, stream>>>(xr, conv_w, conv_b, xs);

    // 4) x_dbl = xs @ wxp^T   (8192 x 128, K=2048)
    gemm_bt<0><<<dim3(NPAD / 128, M / 128), 256, 0, stream>>>(
        xs, wxp, xdbl, nullptr, DI, DI, DI, NPAD);

    // 5) dt = softplus(x_dbl[:, :64] @ W_dt^T + b_dt)   (8192 x 2048, K=64)
    gemm_bt<2><<<dim3(DI / 128, M / 128), 256, 0, stream>>>(
        xdbl, wdtb, dtb, b_dt, DTR, NPAD, DTR, DI);

    // 6) selective scan + D*x + gate -> yg (in-place over xs)
    scan_kernel<<<(Bb * DI) / 16, 256, 0, stream>>>(
        dtb, xs, xdbl, z, A_log, Dvec, yg);

    // 7) out = yg @ W_out^T   (8192 x 1024, K=2048), fp32 store
    gemm_bt<1><<<dim3(DM / 128, M / 128), 256, 0, stream>>>(
        yg, woutb, d_out, nullptr, DI, DI, DI, DM);
}

// Round 3
// 859.419 us; speedup vs baseline: 2.5528x; 2.5528x over previous
//
#include <hip/hip_runtime.h>
#include <math.h>

typedef unsigned short u16;
typedef unsigned int u32;

// ---- problem constants ----
constexpr int Bb = 4, Ll = 2048, DM = 1024, DI = 2048, DS = 16, DTR = 64, KC = 4;
constexpr int M = Bb * Ll;            // 8192 rows
constexpr int NPAD = 128;             // padded x_dbl width (64 + 2*16 = 96 -> 128)
constexpr int NCHUNK = 16;            // scan chunks
constexpr int LC = Ll / NCHUNK;       // 128 steps per chunk

// ---- bf16 helpers on raw u16 ----
__device__ __forceinline__ float b2f(u16 u) {
    return __uint_as_float(((u32)u) << 16);
}
__device__ __forceinline__ u16 f2b(float f) {
    u32 x = __float_as_uint(f);
    u32 r = (x + 0x7fffu + ((x >> 16) & 1u)) >> 16;   // round-to-nearest-even
    return (u16)r;
}

typedef __attribute__((ext_vector_type(8))) short short8;
typedef __attribute__((ext_vector_type(4))) float floatx4;

// =====================================================================
// C(MxN) = A(MxK) * B(NxK)^T, bf16 in, fp32 MFMA acc.
// Block = 256 thr = 4 waves, each wave 64x64, block tile 128x128.
// OUTM: 0 = bf16 store, 1 = fp32 store, 2 = softplus(acc + bias_f32[n]) bf16
// =====================================================================
template<int OUTM>
__global__ __launch_bounds__(256) void gemm_bt(
    const u16* __restrict__ A, const u16* __restrict__ Bm,
    void* __restrict__ Cv, const float* __restrict__ bias,
    int K, int lda, int ldb, int ldc)
{
    const int lane = threadIdx.x & 63;
    const int wave = threadIdx.x >> 6;
    const int wr = wave >> 1, wc = wave & 1;
    const int m0 = blockIdx.y * 128 + wr * 64;
    const int n0 = blockIdx.x * 128 + wc * 64;
    const int r16 = lane & 15;
    const int quad = lane >> 4;
    const int kbase = quad * 8;

    floatx4 acc[4][4] = {};

    const u16* Aptr = A + (size_t)(m0 + r16) * lda + kbase;
    const u16* Bptr = Bm + (size_t)(n0 + r16) * ldb + kbase;

    for (int k = 0; k < K; k += 32) {
        short8 af[4], bf[4];
#pragma unroll
        for (int i = 0; i < 4; i++)
            af[i] = *(const short8*)(Aptr + (size_t)(i * 16) * lda + k);
#pragma unroll
        for (int j = 0; j < 4; j++)
            bf[j] = *(const short8*)(Bptr + (size_t)(j * 16) * ldb + k);
#pragma unroll
        for (int i = 0; i < 4; i++)
#pragma unroll
            for (int j = 0; j < 4; j++)
                acc[i][j] = __builtin_amdgcn_mfma_f32_16x16x32_bf16(
                    af[i], bf[j], acc[i][j], 0, 0, 0);
    }

    // D layout: col = lane&15, row = quad*4 + r   [verified m89/m91]
    const int col = lane & 15;
    const int rb = quad * 4;
#pragma unroll
    for (int i = 0; i < 4; i++) {
#pragma unroll
        for (int j = 0; j < 4; j++) {
            const int n = n0 + j * 16 + col;
#pragma unroll
            for (int r = 0; r < 4; r++) {
                const int m = m0 + i * 16 + rb + r;
                float v = acc[i][j][r];
                if (OUTM == 2) {
                    v += bias[n];
                    v = (v > 20.f) ? v : log1pf(__expf(v));
                }
                if (OUTM == 1)
                    ((float*)Cv)[(size_t)m * ldc + n] = v;
                else
                    ((u16*)Cv)[(size_t)m * ldc + n] = f2b(v);
            }
        }
    }
}

// =====================================================================
__global__ __launch_bounds__(256) void cvt_f2b(
    const float* __restrict__ in, u16* __restrict__ out, int n)
{
    int i = blockIdx.x * blockDim.x + threadIdx.x;
    if (i < n) out[i] = f2b(in[i]);
}

__global__ __launch_bounds__(256) void pad_wx(
    const float* __restrict__ W_x, u16* __restrict__ out)
{
    int idx = blockIdx.x * blockDim.x + threadIdx.x;   // over 128*2048
    int r = idx >> 11;
    int c = idx & 2047;
    out[idx] = (r < 96) ? f2b(W_x[r * 2048 + c]) : (u16)0;
}

// =====================================================================
// Depthwise causal conv (K=4) + SiLU.
// =====================================================================
__global__ __launch_bounds__(256) void conv_silu(
    const u16* __restrict__ xr, const float* __restrict__ conv_w,
    const float* __restrict__ conv_b, u16* __restrict__ xs)
{
    int idx = blockIdx.x * blockDim.x + threadIdx.x;   // over M*DI
    int m = idx >> 11;
    int d = idx & 2047;
    int l = m & (Ll - 1);

    float acc = conv_b[d];
#pragma unroll
    for (int k = 0; k < KC; k++) {
        int li = l - (KC - 1) + k;
        if (li >= 0)
            acc += b2f(xr[(size_t)(m - (KC - 1) + k) * DI + d]) * conv_w[d * KC + k];
    }
    float s = acc / (1.f + __expf(-acc));
    xs[(size_t)m * DI + d] = f2b(s);
}

// =====================================================================
// Chunked selective scan.  One THREAD per (channel, chunk); 16 states in
// registers.  dt/xs loads coalesced across d; B/C are wave-uniform
// broadcast vector loads.
//
// P1: local scan (h_in = 0) -> P = prod(a), hend.
// P2: serial combine over chunks -> h_in written in place of P.
// P3: re-run chunk from h_in, y = h.C + D*x, gate with silu(z), store yg.
// =====================================================================
__global__ __launch_bounds__(256) void scan_p1(
    const u16* __restrict__ dtb, const u16* __restrict__ xs,
    const u16* __restrict__ xdbl, const float* __restrict__ A_log,
    float* __restrict__ scr_P, float* __restrict__ scr_hend)
{
    const int d = blockIdx.x * 256 + threadIdx.x;
    const int b = blockIdx.y;
    const int c = blockIdx.z;

    float adiag[DS];
#pragma unroll
    for (int s = 0; s < DS; s++) adiag[s] = -__expf(A_log[s]);

    const int m0 = b * Ll + c * LC;
    const u16* dt_p = dtb + (size_t)m0 * DI + d;
    const u16* xs_p = xs + (size_t)m0 * DI + d;
    const u16* bc_p = xdbl + (size_t)m0 * NPAD + 64;

    float h[DS] = {};
    float P[DS];
#pragma unroll
    for (int s = 0; s < DS; s++) P[s] = 1.f;

    for (int l = 0; l < LC; l++) {
        float dtv = b2f(dt_p[0]);
        float xv  = b2f(xs_p[0]);
        short8 bq0 = *(const short8*)(bc_p);      // B[0..7]
        short8 bq1 = *(const short8*)(bc_p + 8);  // B[8..15]
        float bx = dtv * xv;
#pragma unroll
        for (int s = 0; s < DS; s++) {
            float a = __expf(dtv * adiag[s]);
            float Bv = b2f((u16)(s < 8 ? bq0[s] : bq1[s - 8]));
            h[s] = a * h[s] + bx * Bv;
            P[s] *= a;
        }
        dt_p += DI; xs_p += DI; bc_p += NPAD;
    }

    const size_t base = ((size_t)(b * NCHUNK + c) * DI + d) * DS;
#pragma unroll
    for (int s = 0; s < DS; s += 4) {
        *(floatx4*)(scr_P + base + s)    = *(floatx4*)(P + s);
        *(floatx4*)(scr_hend + base + s) = *(floatx4*)(h + s);
    }
}

__global__ __launch_bounds__(256) void scan_p2(
    float* __restrict__ scr_P, const float* __restrict__ scr_hend)
{
    // one thread per (b, d, s): 4*2048*16 = 131072 threads
    const int t = blockIdx.x * 256 + threadIdx.x;
    const int s = t & 15;
    const int d = (t >> 4) & (DI - 1);
    const int b = t >> 15;

    float hin = 0.f;
    for (int c = 0; c < NCHUNK; c++) {
        const size_t base = ((size_t)(b * NCHUNK + c) * DI + d) * DS + s;
        float p = scr_P[base];
        float he = scr_hend[base];
        scr_P[base] = hin;             // overwrite P with h_in for chunk c
        hin = p * hin + he;
    }
}

__global__ __launch_bounds__(256) void scan_p3(
    const u16* __restrict__ dtb, const u16* xs, const u16* __restrict__ xdbl,
    const u16* __restrict__ z, const float* __restrict__ scr_hin,
    const float* __restrict__ A_log, const float* __restrict__ Dvec,
    u16* yg)
{
    const int d = blockIdx.x * 256 + threadIdx.x;
    const int b = blockIdx.y;
    const int c = blockIdx.z;

    float adiag[DS];
#pragma unroll
    for (int s = 0; s < DS; s++) adiag[s] = -__expf(A_log[s]);
    const float Dd = Dvec[d];

    const int m0 = b * Ll + c * LC;
    const u16* dt_p = dtb + (size_t)m0 * DI + d;
    const u16* xs_p = xs + (size_t)m0 * DI + d;
    const u16* z_p  = z + (size_t)m0 * DI + d;
    const u16* bc_p = xdbl + (size_t)m0 * NPAD + 64;
    u16* yg_p = yg + (size_t)m0 * DI + d;

    float h[DS];
    const size_t base = ((size_t)(b * NCHUNK + c) * DI + d) * DS;
#pragma unroll
    for (int s = 0; s < DS; s += 4)
        *(floatx4*)(h + s) = *(const floatx4*)(scr_hin + base + s);

    for (int l = 0; l < LC; l++) {
        float dtv = b2f(dt_p[0]);
        float xv  = b2f(xs_p[0]);
        short8 bq0 = *(const short8*)(bc_p);       // B[0..7]
        short8 bq1 = *(const short8*)(bc_p + 8);   // B[8..15]
        short8 cq0 = *(const short8*)(bc_p + 16);  // C[0..7]
        short8 cq1 = *(const short8*)(bc_p + 24);  // C[8..15]
        float bx = dtv * xv;
        float y = Dd * xv;
#pragma unroll
        for (int s = 0; s < DS; s++) {
            float a = __expf(dtv * adiag[s]);
            float Bv = b2f((u16)(s < 8 ? bq0[s] : bq1[s - 8]));
            float Cv = b2f((u16)(s < 8 ? cq0[s] : cq1[s - 8]));
            h[s] = a * h[s] + bx * Bv;
            y += h[s] * Cv;
        }
        float zv = b2f(z_p[0]);
        float g = zv / (1.f + __expf(-zv));
        yg_p[0] = f2b(y * g);

        dt_p += DI; xs_p += DI; z_p += DI; bc_p += NPAD; yg_p += DI;
    }
}

// =====================================================================
extern "C" void kernel_launch(void* const* d_in, const int* in_sizes, int n_in,
                              void* d_out, int out_size, void* d_ws, size_t ws_size,
                              hipStream_t stream)
{
    const float* x      = (const float*)d_in[0];   // (B,L,DM)
    const float* W_in   = (const float*)d_in[1];   // (2*DI, DM)
    const float* conv_w = (const float*)d_in[2];   // (DI, KC)
    const float* conv_b = (const float*)d_in[3];   // (DI,)
    const float* A_log  = (const float*)d_in[4];   // (DS,)
    const float* Dvec   = (const float*)d_in[5];   // (DI,)
    const float* W_x    = (const float*)d_in[6];   // (96, DI)
    const float* W_dt   = (const float*)d_in[7];   // (DI, DTR)
    const float* b_dt   = (const float*)d_in[8];   // (DI,)
    const float* W_out  = (const float*)d_in[9];   // (DM, DI)

    // ---- workspace arena (bf16 u16 elements), ~128.7 MB total ----
    u16* ws = (u16*)d_ws;
    u16* xr    = ws;                 ws += (size_t)M * DI;     // reused as dtb
    u16* z     = ws;                 ws += (size_t)M * DI;
    u16* xs    = ws;                 ws += (size_t)M * DI;     // yg in-place
    u16* xbf   = ws;                 ws += (size_t)M * DM;     // reused as scan scratch
    u16* wibf  = ws;                 ws += (size_t)DI * DM;
    u16* wxp   = ws;                 ws += (size_t)NPAD * DI;
    u16* wdtb  = ws;                 ws += (size_t)DI * DTR;
    u16* woutb = ws;                 ws += (size_t)DM * DI;
    u16* xdbl  = ws;                 ws += (size_t)M * NPAD;
    u16* dtb   = xr;                 // alias (xr dead after conv)
    u16* yg    = xs;                 // in-place (each (m,d) owned by one thread)
    // scan scratch: 2 x (Bb*NCHUNK*DI*DS) floats = 16.78 MB = sizeof(xbf)
    float* scr_P    = (float*)xbf;
    float* scr_hend = scr_P + (size_t)Bb * NCHUNK * DI * DS;

    // 0) conversions for GEMM1 operands
    cvt_f2b<<<(M * DM) / 256, 256, 0, stream>>>(x, xbf, M * DM);
    cvt_f2b<<<(DI * DM) / 256, 256, 0, stream>>>(W_in, wibf, DI * DM);

    // 1a) xr = x @ W_in[0:DI]^T   (8192 x 2048, K=1024)
    gemm_bt<0><<<dim3(DI / 128, M / 128), 256, 0, stream>>>(
        xbf, wibf, xr, nullptr, DM, DM, DM, DI);

    // 1b) z = x @ W_in[DI:2DI]^T
    cvt_f2b<<<(DI * DM) / 256, 256, 0, stream>>>(W_in + (size_t)DI * DM, wibf, DI * DM);
    gemm_bt<0><<<dim3(DI / 128, M / 128), 256, 0, stream>>>(
        xbf, wibf, z, nullptr, DM, DM, DM, DI);

    // 2) remaining weight conversions
    pad_wx<<<(NPAD * DI) / 256, 256, 0, stream>>>(W_x, wxp);
    cvt_f2b<<<(DI * DTR) / 256, 256, 0, stream>>>(W_dt, wdtb, DI * DTR);
    cvt_f2b<<<(DM * DI) / 256, 256, 0, stream>>>(W_out, woutb, DM * DI);

    // 3) conv + silu -> xs
    conv_silu<<<(M * DI) / 256, 256, 0, stream>>>(xr, conv_w, conv_b, xs);

    // 4) x_dbl = xs @ wxp^T   (8192 x 128, K=2048)
    gemm_bt<0><<<dim3(NPAD / 128, M / 128), 256, 0, stream>>>(
        xs, wxp, xdbl, nullptr, DI, DI, DI, NPAD);

    // 5) dt = softplus(x_dbl[:, :64] @ W_dt^T + b_dt)   (8192 x 2048, K=64)
    gemm_bt<2><<<dim3(DI / 128, M / 128), 256, 0, stream>>>(
        xdbl, wdtb, dtb, b_dt, DTR, NPAD, DTR, DI);

    // 6) chunked scan (xbf dead -> scratch)
    scan_p1<<<dim3(DI / 256, Bb, NCHUNK), 256, 0, stream>>>(
        dtb, xs, xdbl, A_log, scr_P, scr_hend);
    scan_p2<<<(Bb * DI * DS) / 256, 256, 0, stream>>>(scr_P, scr_hend);
    scan_p3<<<dim3(DI / 256, Bb, NCHUNK), 256, 0, stream>>>(
        dtb, xs, xdbl, z, scr_P, A_log, Dvec, yg);

    // 7) out = yg @ W_out^T   (8192 x 1024, K=2048), fp32 store
    gemm_bt<1><<<dim3(DM / 128, M / 128), 256, 0, stream>>>(
        yg, woutb, d_out, nullptr, DI, DI, DI, DM);
}

// Round 4
// 647.632 us; speedup vs baseline: 3.3876x; 1.3270x over previous
//
#include <hip/hip_runtime.h>
#include <math.h>

typedef unsigned short u16;
typedef unsigned int u32;

// ---- problem constants ----
constexpr int Bb = 4, Ll = 2048, DM = 1024, DI = 2048, DS = 16, DTR = 64, KC = 4;
constexpr int M = Bb * Ll;            // 8192 rows
constexpr int NPAD = 128;             // padded x_dbl width (64 + 2*16 = 96 -> 128)
constexpr int NCHUNK = 16;            // scan chunks
constexpr int LC = Ll / NCHUNK;       // 128 steps per chunk

// ---- bf16 helpers on raw u16 ----
__device__ __forceinline__ float b2f(u16 u) {
    return __uint_as_float(((u32)u) << 16);
}
__device__ __forceinline__ u16 f2b(float f) {
    u32 x = __float_as_uint(f);
    u32 r = (x + 0x7fffu + ((x >> 16) & 1u)) >> 16;   // round-to-nearest-even
    return (u16)r;
}

typedef __attribute__((ext_vector_type(8))) short short8;
typedef __attribute__((ext_vector_type(4))) float floatx4;

// async global->LDS, 16B per lane; LDS dest = wave-uniform base + lane*16
__device__ __forceinline__ void gload16(const u16* g, u16* l) {
    __builtin_amdgcn_global_load_lds(
        (const __attribute__((address_space(1))) void*)g,
        (__attribute__((address_space(3))) void*)l,
        16, 0, 0);
}

// =====================================================================
// C(MxN) = A(MxK) * B(NxK)^T, bf16 in, fp32 MFMA acc.  m97 structure:
// 128x128 block tile, BK=32, LDS-staged via global_load_lds width=16,
// 4 waves each computing 64x64 (4x4 MFMA 16x16x32 frags).
// OUTM: 0 = bf16 store, 1 = fp32 store, 2 = softplus(acc + bias_f32[n]) bf16
// =====================================================================
template<int OUTM>
__global__ __launch_bounds__(256) void gemm_bt(
    const u16* __restrict__ A, const u16* __restrict__ Bm,
    void* __restrict__ Cv, const float* __restrict__ bias,
    int K, int lda, int ldb, int ldc)
{
    __shared__ alignas(16) u16 ldsA[128 * 32];
    __shared__ alignas(16) u16 ldsB[128 * 32];

    const int lane = threadIdx.x & 63;
    const int wave = threadIdx.x >> 6;
    const int wr = wave >> 1, wc = wave & 1;
    const int m0 = blockIdx.y * 128;
    const int n0 = blockIdx.x * 128;

    // staging map: wave w, inst t in {0,1} covers LDS 16B-chunks
    // [w*128 + t*64 + lane]; chunk c -> row c>>2, k-chunk c&3.
    const int srow = wave * 32 + (lane >> 2);          // + t*16
    const int skc  = (lane & 3) * 8;                    // k elem offset
    const u16* Ag = A + (size_t)(m0 + srow) * lda + skc;
    const u16* Bg = Bm + (size_t)(n0 + srow) * ldb + skc;
    u16* lA = &ldsA[wave * 1024];                       // wave-uniform base
    u16* lB = &ldsB[wave * 1024];

    const int r16 = lane & 15;
    const int quad = lane >> 4;
    const u16* arow = &ldsA[(wr * 64 + r16) * 32 + quad * 8];
    const u16* brow = &ldsB[(wc * 64 + r16) * 32 + quad * 8];

    floatx4 acc[4][4] = {};

    for (int k0 = 0; k0 < K; k0 += 32) {
        gload16(Ag + k0,                    lA);
        gload16(Ag + k0 + (size_t)16 * lda, lA + 512);
        gload16(Bg + k0,                    lB);
        gload16(Bg + k0 + (size_t)16 * ldb, lB + 512);
        __syncthreads();   // drains vmcnt before any lane reads LDS

        short8 af[4], bf[4];
#pragma unroll
        for (int i = 0; i < 4; i++) af[i] = *(const short8*)(arow + i * 16 * 32);
#pragma unroll
        for (int j = 0; j < 4; j++) bf[j] = *(const short8*)(brow + j * 16 * 32);
#pragma unroll
        for (int i = 0; i < 4; i++)
#pragma unroll
            for (int j = 0; j < 4; j++)
                acc[i][j] = __builtin_amdgcn_mfma_f32_16x16x32_bf16(
                    af[i], bf[j], acc[i][j], 0, 0, 0);
        __syncthreads();   // protect LDS from next-iter staging
    }

    // D layout: col = lane&15, row = quad*4 + r   [verified m89/m91]
    const int mw = m0 + wr * 64;
    const int nw = n0 + wc * 64;
    const int rb = quad * 4;
#pragma unroll
    for (int i = 0; i < 4; i++) {
#pragma unroll
        for (int j = 0; j < 4; j++) {
            const int n = nw + j * 16 + r16;
#pragma unroll
            for (int r = 0; r < 4; r++) {
                const int m = mw + i * 16 + rb + r;
                float v = acc[i][j][r];
                if (OUTM == 2) {
                    v += bias[n];
                    v = (v > 20.f) ? v : log1pf(__expf(v));
                }
                if (OUTM == 1)
                    ((float*)Cv)[(size_t)m * ldc + n] = v;
                else
                    ((u16*)Cv)[(size_t)m * ldc + n] = f2b(v);
            }
        }
    }
}

// =====================================================================
__global__ __launch_bounds__(256) void cvt_f2b(
    const float* __restrict__ in, u16* __restrict__ out, int n)
{
    int i = blockIdx.x * blockDim.x + threadIdx.x;
    if (i < n) out[i] = f2b(in[i]);
}

__global__ __launch_bounds__(256) void pad_wx(
    const float* __restrict__ W_x, u16* __restrict__ out)
{
    int idx = blockIdx.x * blockDim.x + threadIdx.x;   // over 128*2048
    int r = idx >> 11;
    int c = idx & 2047;
    out[idx] = (r < 96) ? f2b(W_x[r * 2048 + c]) : (u16)0;
}

// =====================================================================
// Depthwise causal conv (K=4) + SiLU.
// =====================================================================
__global__ __launch_bounds__(256) void conv_silu(
    const u16* __restrict__ xr, const float* __restrict__ conv_w,
    const float* __restrict__ conv_b, u16* __restrict__ xs)
{
    int idx = blockIdx.x * blockDim.x + threadIdx.x;   // over M*DI
    int m = idx >> 11;
    int d = idx & 2047;
    int l = m & (Ll - 1);

    float acc = conv_b[d];
#pragma unroll
    for (int k = 0; k < KC; k++) {
        int li = l - (KC - 1) + k;
        if (li >= 0)
            acc += b2f(xr[(size_t)(m - (KC - 1) + k) * DI + d]) * conv_w[d * KC + k];
    }
    float s = acc / (1.f + __expf(-acc));
    xs[(size_t)m * DI + d] = f2b(s);
}

// =====================================================================
// Chunked selective scan.  One THREAD per (channel, chunk); 16 states in
// registers.  dt/xs loads coalesced across d; B/C wave-uniform broadcast.
// =====================================================================
__global__ __launch_bounds__(256) void scan_p1(
    const u16* __restrict__ dtb, const u16* __restrict__ xs,
    const u16* __restrict__ xdbl, const float* __restrict__ A_log,
    float* __restrict__ scr_P, float* __restrict__ scr_hend)
{
    const int d = blockIdx.x * 256 + threadIdx.x;
    const int b = blockIdx.y;
    const int c = blockIdx.z;

    float adiag[DS];
#pragma unroll
    for (int s = 0; s < DS; s++) adiag[s] = -__expf(A_log[s]);

    const int m0 = b * Ll + c * LC;
    const u16* dt_p = dtb + (size_t)m0 * DI + d;
    const u16* xs_p = xs + (size_t)m0 * DI + d;
    const u16* bc_p = xdbl + (size_t)m0 * NPAD + 64;

    float h[DS] = {};
    float P[DS];
#pragma unroll
    for (int s = 0; s < DS; s++) P[s] = 1.f;

    for (int l = 0; l < LC; l++) {
        float dtv = b2f(dt_p[0]);
        float xv  = b2f(xs_p[0]);
        short8 bq0 = *(const short8*)(bc_p);
        short8 bq1 = *(const short8*)(bc_p + 8);
        float bx = dtv * xv;
#pragma unroll
        for (int s = 0; s < DS; s++) {
            float a = __expf(dtv * adiag[s]);
            float Bv = b2f((u16)(s < 8 ? bq0[s] : bq1[s - 8]));
            h[s] = a * h[s] + bx * Bv;
            P[s] *= a;
        }
        dt_p += DI; xs_p += DI; bc_p += NPAD;
    }

    const size_t base = ((size_t)(b * NCHUNK + c) * DI + d) * DS;
#pragma unroll
    for (int s = 0; s < DS; s += 4) {
        *(floatx4*)(scr_P + base + s)    = *(floatx4*)(P + s);
        *(floatx4*)(scr_hend + base + s) = *(floatx4*)(h + s);
    }
}

__global__ __launch_bounds__(256) void scan_p2(
    float* __restrict__ scr_P, const float* __restrict__ scr_hend)
{
    const int t = blockIdx.x * 256 + threadIdx.x;   // (b, d, s)
    const int s = t & 15;
    const int d = (t >> 4) & (DI - 1);
    const int b = t >> 15;

    float hin = 0.f;
    for (int c = 0; c < NCHUNK; c++) {
        const size_t base = ((size_t)(b * NCHUNK + c) * DI + d) * DS + s;
        float p = scr_P[base];
        float he = scr_hend[base];
        scr_P[base] = hin;
        hin = p * hin + he;
    }
}

__global__ __launch_bounds__(256) void scan_p3(
    const u16* __restrict__ dtb, const u16* xs, const u16* __restrict__ xdbl,
    const u16* __restrict__ z, const float* __restrict__ scr_hin,
    const float* __restrict__ A_log, const float* __restrict__ Dvec,
    u16* yg)
{
    const int d = blockIdx.x * 256 + threadIdx.x;
    const int b = blockIdx.y;
    const int c = blockIdx.z;

    float adiag[DS];
#pragma unroll
    for (int s = 0; s < DS; s++) adiag[s] = -__expf(A_log[s]);
    const float Dd = Dvec[d];

    const int m0 = b * Ll + c * LC;
    const u16* dt_p = dtb + (size_t)m0 * DI + d;
    const u16* xs_p = xs + (size_t)m0 * DI + d;
    const u16* z_p  = z + (size_t)m0 * DI + d;
    const u16* bc_p = xdbl + (size_t)m0 * NPAD + 64;
    u16* yg_p = yg + (size_t)m0 * DI + d;

    float h[DS];
    const size_t base = ((size_t)(b * NCHUNK + c) * DI + d) * DS;
#pragma unroll
    for (int s = 0; s < DS; s += 4)
        *(floatx4*)(h + s) = *(const floatx4*)(scr_hin + base + s);

    for (int l = 0; l < LC; l++) {
        float dtv = b2f(dt_p[0]);
        float xv  = b2f(xs_p[0]);
        short8 bq0 = *(const short8*)(bc_p);
        short8 bq1 = *(const short8*)(bc_p + 8);
        short8 cq0 = *(const short8*)(bc_p + 16);
        short8 cq1 = *(const short8*)(bc_p + 24);
        float bx = dtv * xv;
        float y = Dd * xv;
#pragma unroll
        for (int s = 0; s < DS; s++) {
            float a = __expf(dtv * adiag[s]);
            float Bv = b2f((u16)(s < 8 ? bq0[s] : bq1[s - 8]));
            float Cv = b2f((u16)(s < 8 ? cq0[s] : cq1[s - 8]));
            h[s] = a * h[s] + bx * Bv;
            y += h[s] * Cv;
        }
        float zv = b2f(z_p[0]);
        float g = zv / (1.f + __expf(-zv));
        yg_p[0] = f2b(y * g);

        dt_p += DI; xs_p += DI; z_p += DI; bc_p += NPAD; yg_p += DI;
    }
}

// =====================================================================
extern "C" void kernel_launch(void* const* d_in, const int* in_sizes, int n_in,
                              void* d_out, int out_size, void* d_ws, size_t ws_size,
                              hipStream_t stream)
{
    const float* x      = (const float*)d_in[0];   // (B,L,DM)
    const float* W_in   = (const float*)d_in[1];   // (2*DI, DM)
    const float* conv_w = (const float*)d_in[2];   // (DI, KC)
    const float* conv_b = (const float*)d_in[3];   // (DI,)
    const float* A_log  = (const float*)d_in[4];   // (DS,)
    const float* Dvec   = (const float*)d_in[5];   // (DI,)
    const float* W_x    = (const float*)d_in[6];   // (96, DI)
    const float* W_dt   = (const float*)d_in[7];   // (DI, DTR)
    const float* b_dt   = (const float*)d_in[8];   // (DI,)
    const float* W_out  = (const float*)d_in[9];   // (DM, DI)

    // ---- workspace arena (bf16 u16 elements), ~133 MB total ----
    u16* ws = (u16*)d_ws;
    u16* xr    = ws;                 ws += (size_t)M * DI;       // reused as dtb
    u16* z     = ws;                 ws += (size_t)M * DI;
    u16* xs    = ws;                 ws += (size_t)M * DI;       // yg in-place
    u16* xbf   = ws;                 ws += (size_t)M * DM;       // reused as scan scratch
    u16* wibf  = ws;                 ws += (size_t)2 * DI * DM;  // full W_in
    u16* wxp   = ws;                 ws += (size_t)NPAD * DI;
    u16* wdtb  = ws;                 ws += (size_t)DI * DTR;
    u16* woutb = ws;                 ws += (size_t)DM * DI;
    u16* xdbl  = ws;                 ws += (size_t)M * NPAD;
    u16* dtb   = xr;                 // alias (xr dead after conv)
    u16* yg    = xs;                 // in-place (each (m,d) owned by one thread)
    float* scr_P    = (float*)xbf;   // scan scratch reuses dead xbf (16.78 MB)
    float* scr_hend = scr_P + (size_t)Bb * NCHUNK * DI * DS;

    // 0) conversions for GEMM operands
    cvt_f2b<<<(M * DM) / 256, 256, 0, stream>>>(x, xbf, M * DM);
    cvt_f2b<<<(2 * DI * DM) / 256, 256, 0, stream>>>(W_in, wibf, 2 * DI * DM);
    pad_wx<<<(NPAD * DI) / 256, 256, 0, stream>>>(W_x, wxp);
    cvt_f2b<<<(DI * DTR) / 256, 256, 0, stream>>>(W_dt, wdtb, DI * DTR);
    cvt_f2b<<<(DM * DI) / 256, 256, 0, stream>>>(W_out, woutb, DM * DI);

    // 1a) xr = x @ W_in[0:DI]^T   (8192 x 2048, K=1024)
    gemm_bt<0><<<dim3(DI / 128, M / 128), 256, 0, stream>>>(
        xbf, wibf, xr, nullptr, DM, DM, DM, DI);
    // 1b) z = x @ W_in[DI:2DI]^T
    gemm_bt<0><<<dim3(DI / 128, M / 128), 256, 0, stream>>>(
        xbf, wibf + (size_t)DI * DM, z, nullptr, DM, DM, DM, DI);

    // 2) conv + silu -> xs
    conv_silu<<<(M * DI) / 256, 256, 0, stream>>>(xr, conv_w, conv_b, xs);

    // 3) x_dbl = xs @ wxp^T   (8192 x 128, K=2048)
    gemm_bt<0><<<dim3(NPAD / 128, M / 128), 256, 0, stream>>>(
        xs, wxp, xdbl, nullptr, DI, DI, DI, NPAD);

    // 4) dt = softplus(x_dbl[:, :64] @ W_dt^T + b_dt)   (8192 x 2048, K=64)
    gemm_bt<2><<<dim3(DI / 128, M / 128), 256, 0, stream>>>(
        xdbl, wdtb, dtb, b_dt, DTR, NPAD, DTR, DI);

    // 5) chunked scan (xbf dead -> scratch)
    scan_p1<<<dim3(DI / 256, Bb, NCHUNK), 256, 0, stream>>>(
        dtb, xs, xdbl, A_log, scr_P, scr_hend);
    scan_p2<<<(Bb * DI * DS) / 256, 256, 0, stream>>>(scr_P, scr_hend);
    scan_p3<<<dim3(DI / 256, Bb, NCHUNK), 256, 0, stream>>>(
        dtb, xs, xdbl, z, scr_P, A_log, Dvec, yg);

    // 6) out = yg @ W_out^T   (8192 x 1024, K=2048), fp32 store
    gemm_bt<1><<<dim3(DM / 128, M / 128), 256, 0, stream>>>(
        yg, woutb, d_out, nullptr, DI, DI, DI, DM);
}